// Round 1
// baseline (253.034 us; speedup 1.0000x reference)
//
#include <hip/hip_runtime.h>

// shift op: out[b, g*32+c, h, w] = x[b, g*32+c, h+dh, w+dw] (zero outside),
// groups g=0..7 with offsets; channels 256..287 stay zero.
// (32, 288, 64, 64) fp32. Pure memory-bound shuffle: 285 MB total -> ~45us floor.
//
// v2: one 256-thread block per (b,c) plane. Each thread owns 4 independent
// float4 segments (rows r0, r0+16, r0+32, r0+48) -> 4 outstanding
// global_load_dwordx4 per thread before the first vmcnt wait (4x the MLP of
// v1), and 4x fewer blocks (9216). The w+-1 shift is still reconstructed via
// one cross-lane __shfl per segment (lane+-1 holds the adjacent float4 of the
// same row; 16 lanes per row, masked at the row edge).

#define CC  288
#define HH  64
#define WW  64

__global__ __launch_bounds__(256) void shift_kernel(const float* __restrict__ x,
                                                    float* __restrict__ out) {
    const int plane = blockIdx.x;            // b*C + c   (0..9215)
    const int c     = plane % CC;
    const int g     = c >> 5;                // c / 32

    const int t  = threadIdx.x;              // 0..255
    const int w0 = (t & 15) << 2;            // 0,4,...,60
    const int r0 = t >> 4;                   // 0..15  (rows r0 + 16k)

    float* __restrict__ obase = out + (size_t)plane * (HH * WW);

    if (g >= 8) {                            // group 8: stays zero
        const float4 z = make_float4(0.f, 0.f, 0.f, 0.f);
        #pragma unroll
        for (int k = 0; k < 4; ++k)
            *(float4*)(obase + (r0 + (k << 4)) * WW + w0) = z;
        return;
    }

    // offsets: g0(-1,0) g1(1,0) g2(0,-1) g3(0,1) g4(-1,-1) g5(-1,1) g6(1,-1) g7(1,1)
    const int dh = (int)((0x22001120u >> (g * 4)) & 0xFu) - 1;
    const int dw = (int)((0x20202011u >> (g * 4)) & 0xFu) - 1;

    const float* __restrict__ ibase = x + (size_t)plane * (HH * WW);

    // 4 independent aligned 16B loads issued back-to-back (MLP), zero-filled
    // at the h boundary (only the edge row-group diverges, and only for dh!=0)
    float4 a[4];
    #pragma unroll
    for (int k = 0; k < 4; ++k) {
        const int hs = r0 + (k << 4) + dh;
        if ((unsigned)hs < (unsigned)HH)
            a[k] = *(const float4*)(ibase + hs * WW + w0);
        else
            a[k] = make_float4(0.f, 0.f, 0.f, 0.f);
    }

    const int lane = t & 63;                 // 16 lanes per row within the wave
    if (dw == 0) {                           // wave-uniform branch (g uniform/block)
        #pragma unroll
        for (int k = 0; k < 4; ++k)
            *(float4*)(obase + (r0 + (k << 4)) * WW + w0) = a[k];
    } else if (dw == 1) {
        #pragma unroll
        for (int k = 0; k < 4; ++k) {
            // out[w] = row[w+1]; row[w0+4] == lane+1's a.x (same row: 16-lane groups)
            float nx = __shfl(a[k].x, (lane + 1) & 63);
            float4 v;
            v.x = a[k].y; v.y = a[k].z; v.z = a[k].w;
            v.w = (w0 == 60) ? 0.f : nx;     // row boundary -> zero (also masks group edge)
            *(float4*)(obase + (r0 + (k << 4)) * WW + w0) = v;
        }
    } else {
        #pragma unroll
        for (int k = 0; k < 4; ++k) {
            // out[w] = row[w-1]; row[w0-1] == lane-1's a.w
            float pw = __shfl(a[k].w, (lane - 1) & 63);
            float4 v;
            v.x = (w0 == 0) ? 0.f : pw;
            v.y = a[k].x; v.z = a[k].y; v.w = a[k].z;
            *(float4*)(obase + (r0 + (k << 4)) * WW + w0) = v;
        }
    }
}

extern "C" void kernel_launch(void* const* d_in, const int* in_sizes, int n_in,
                              void* d_out, int out_size, void* d_ws, size_t ws_size,
                              hipStream_t stream) {
    const float* x = (const float*)d_in[0];
    float* out = (float*)d_out;
    // 1 block per (b,c) plane; 256 threads x 4 float4 = 4096 floats = 64 rows
    shift_kernel<<<dim3(32 * CC), dim3(256), 0, stream>>>(x, out);
}

// Round 3
// 238.865 us; speedup vs baseline: 1.0593x; 1.0593x over previous
//
#include <hip/hip_runtime.h>

// shift op: out[b, g*32+c, h, w] = x[b, g*32+c, h+dh, w+dw] (zero outside),
// groups g=0..7 with offsets; channels 256..287 stay zero.
// (32, 288, 64, 64) fp32. Pure memory-bound shuffle: 285 MB total -> ~45us floor.
//
// v3b = v1 (proven 240.9us shape: 4 blocks/plane, one dwordx4 load + one
// dwordx4 store + one cross-lane __shfl per thread) + nontemporal hints on
// both streams. x is read exactly once and out written exactly once (zero
// reuse), so the nt bit (evict-first) stops the output write-allocate from
// polluting L2/L3. Uses a clang ext_vector float4 (v4f) because
// __builtin_nontemporal_* rejects HIP_vector_type<float,4>.
// [v2 post-mortem: 4x per-thread MLP with 1 block/plane REGRESSED 59->71us
//  kernel time -- TLP already saturated at 36864 blocks; keep the v1 grid.]

#define CC  288
#define HH  64
#define WW  64

typedef float v4f __attribute__((ext_vector_type(4)));

__global__ __launch_bounds__(256) void shift_kernel(const float* __restrict__ x,
                                                    float* __restrict__ out) {
    const int blk     = blockIdx.x;
    const int plane   = blk >> 2;            // b*C + c   (0..9215)
    const int quarter = blk & 3;             // 16-row slab
    const int c       = plane % CC;
    const int g       = c >> 5;              // c / 32

    const int t  = threadIdx.x;              // 0..255
    const int w0 = (t & 15) << 2;            // 0,4,...,60
    const int h  = (quarter << 4) + (t >> 4);

    v4f* dst = (v4f*)(out + (size_t)plane * (HH * WW) + h * WW + w0);

    if (g >= 8) {                            // group 8: stays zero
        __builtin_nontemporal_store((v4f){0.f, 0.f, 0.f, 0.f}, dst);
        return;
    }

    // offsets: g0(-1,0) g1(1,0) g2(0,-1) g3(0,1) g4(-1,-1) g5(-1,1) g6(1,-1) g7(1,1)
    const int dh = (int)((0x22001120u >> (g * 4)) & 0xFu) - 1;
    const int dw = (int)((0x20202011u >> (g * 4)) & 0xFu) - 1;

    const int hs = h + dh;
    if ((unsigned)hs >= (unsigned)HH) {      // whole row out of bounds -> zero
        __builtin_nontemporal_store((v4f){0.f, 0.f, 0.f, 0.f}, dst);
        return;
    }

    const float* __restrict__ row = x + (size_t)plane * (HH * WW) + hs * WW;

    // single aligned 16B nontemporal load of this thread's source row segment
    v4f a = __builtin_nontemporal_load((const v4f*)(row + w0));

    v4f v;
    const int lane = t & 63;
    if (dw == 0) {
        v = a;
    } else if (dw == 1) {
        // out[w] = row[w+1]; row[w0+4] == lane+1's a.x (same row: lanes 0..15)
        float nx = __shfl(a.x, lane + 1);
        v.x = a.y; v.y = a.z; v.z = a.w;
        v.w = (w0 == 60) ? 0.f : nx;         // row boundary -> zero (also masks wave edge)
    } else {
        // out[w] = row[w-1]; row[w0-1] == lane-1's a.w
        float pw = __shfl(a.w, lane - 1);
        v.x = (w0 == 0) ? 0.f : pw;
        v.y = a.x; v.z = a.y; v.w = a.z;
    }
    __builtin_nontemporal_store(v, dst);
}

extern "C" void kernel_launch(void* const* d_in, const int* in_sizes, int n_in,
                              void* d_out, int out_size, void* d_ws, size_t ws_size,
                              hipStream_t stream) {
    const float* x = (const float*)d_in[0];
    float* out = (float*)d_out;
    // 4 blocks per (b,c) plane; 256 threads x float4 = 1024 floats = 16 rows
    shift_kernel<<<dim3(32 * CC * 4), dim3(256), 0, stream>>>(x, out);
}